// Round 4
// baseline (284.523 us; speedup 1.0000x reference)
//
#include <hip/hip_runtime.h>

#define BB 64
#define TT 512
#define HH 1024
#define CC 21
#define NROWS (BB*TT)   // 32768

#define AS1 __attribute__((address_space(1)))
#define AS3 __attribute__((address_space(3)))

typedef short bf16x8 __attribute__((ext_vector_type(8)));   // 8 bf16 = 4 VGPRs
typedef float f32x4  __attribute__((ext_vector_type(4)));

// Dekker-style truncation split of 8 fp32 -> bf16 hi + bf16 lo fragments.
// hi = top16(x) (exact residual), lo = top16(x - hi). Packing matches the
// MFMA element order (dword d = (e_{2d+1}<<16)|e_{2d}).
__device__ __forceinline__ void cvt8(const float x[8], bf16x8& hi, bf16x8& lo) {
  float r[8];
#pragma unroll
  for (int i = 0; i < 8; ++i)
    r[i] = x[i] - __uint_as_float(__float_as_uint(x[i]) & 0xffff0000u);
  union { unsigned u[4]; bf16x8 v; } H, L;
#pragma unroll
  for (int d = 0; d < 4; ++d) {
    H.u[d] = __builtin_amdgcn_perm(__float_as_uint(x[2*d+1]), __float_as_uint(x[2*d]), 0x07060302u);
    L.u[d] = __builtin_amdgcn_perm(__float_as_uint(r[2*d+1]), __float_as_uint(r[2*d]), 0x07060302u);
  }
  hi = H.v; lo = L.v;
}

// ---------------------------------------------------------------------------
// Kernel 1: emissions = hs @ W + b.  (v8: MFMA, bf16 hi/lo split)
//
// R3 post-mortem: v6/v7's 12.7k cy/chunk == 672 readlane->fma SGPR-dependency
// pairs/SIMD/chunk at ~16cy exposed each. Every W-broadcast scheme (ds
// broadcast / s_load / readlane) costs >= the FMAs -> VALU formulation is
// structurally capped at ~78us. v8 lets the MFMA unit do the broadcast:
//  - fp32 -> bf16 hi+lo truncation split, D = Ahi*Bhi + Alo*Bhi + Ahi*Blo
//    (worst-case err ~1.1e-3 << 7.8e-3 tol).
//  - W converted ONCE to LDS bf16 frag layout (hi+lo, 86KB), XOR-swizzled
//    (8B units, u8^(col&7)) -> ~2-way-conflict float2 frag reads.
//  - hs staged via global_load_lds(16B) into a WAVE-PRIVATE 4-slot ring
//    (2KB chunks = 16 rows x 32k), counted vmcnt(4), 3 chunks in flight,
//    ZERO main-loop barriers.
//  - 256 blocks x 512 thr (8 waves); block = 128 rows, wave = 16 rows,
//    full K per wave -> no cross-wave reduction; direct global epilogue.
// LDS 148 KB -> 1 block/CU, 1 pass.
// ---------------------------------------------------------------------------
__global__ __launch_bounds__(512, 2) void emis_gemm(const float* __restrict__ hs,
                                                    const float* __restrict__ W,
                                                    const float* __restrict__ bias,
                                                    float* __restrict__ out) {
  __shared__ float lds[37888];                       // 151552 B
  float* ring = lds;                                 // [0, 65536) B : 8 waves x 4 x 2KB
  unsigned short* Whi = (unsigned short*)((char*)lds + 65536);    // 43008 B
  unsigned short* Wlo = (unsigned short*)((char*)lds + 108544);   // 43008 B

  const int tid  = threadIdx.x;
  const int lane = tid & 63;
  const int w    = __builtin_amdgcn_readfirstlane(tid >> 6);
  const int row0 = blockIdx.x * 128;

  if (blockIdx.x == 0 && tid == 0) out[(size_t)NROWS * CC] = 0.f;  // loss slot

  // ---- convert W -> LDS bf16 hi/lo, col-major [21][1024], XOR-swizzled ----
  // u16 offset = col*1024 + ((k>>2)^(col&7))*4 + (k&3)
#pragma unroll
  for (int i = 0; i < 42; ++i) {
    int e = tid + i * 512;                 // 0..21503
    int k = e / 21;
    int c = e - k * 21;
    float x = W[e];
    unsigned hb = __float_as_uint(x) & 0xffff0000u;
    float r = x - __uint_as_float(hb);
    int off = c * 1024 + (((k >> 2) ^ (c & 7)) << 2) + (k & 3);
    Whi[off] = (unsigned short)(hb >> 16);
    Wlo[off] = (unsigned short)(__float_as_uint(r) >> 16);
  }

  // ---- per-lane constants ----
  const int g   = lane >> 4;               // 0..3 (16-lane group)
  const int x7  = lane & 7;
  const int ce0 = lane & 15;                              // ntile0 col 0..15
  const int m5  = (lane & 15) < 5;
  const int ce1 = m5 ? 16 + (lane & 15) : 16;             // ntile1 col (bcast pad)
  const int ce1_7 = ce1 & 7;

  // staging: instr0 = rows 0-7 of wave tile, instr1 = rows 8-15.
  // source slot pre-swizzled (l&7)^(l>>3) so linear LDS dest = swizzled tile.
  const float* P0 = hs + (size_t)(row0 + 16 * w + (lane >> 3)) * HH + ((lane & 7) ^ (lane >> 3)) * 4;
  const float* P1 = P0 + (size_t)8 * HH;
  float* ringw = ring + w * 2048;          // 4 slots x 512 floats (16 rows x 32k)

  __syncthreads();                         // W frags visible to all waves

  f32x4 acc0 = {0.f, 0.f, 0.f, 0.f};
  f32x4 acc1 = {0.f, 0.f, 0.f, 0.f};

  auto stage = [&](int c) {
    float* dstb = ringw + (c & 3) * 512;   // wave-uniform base; HW adds lane*16
    __builtin_amdgcn_global_load_lds((const AS1 unsigned int*)(P0 + c * 32),
                                     (AS3 unsigned int*)dstb, 16, 0, 0);
    __builtin_amdgcn_global_load_lds((const AS1 unsigned int*)(P1 + c * 32),
                                     (AS3 unsigned int*)(dstb + 256), 16, 0, 0);
  };

  auto compute = [&](int c) {
    // A: this lane's row, 8 fp32 (k = c*32 + 4g+{0..3} and +16)
    const float* tb = ringw + (c & 3) * 512 + (lane & 15) * 32;
    float4 ra = *reinterpret_cast<const float4*>(tb + ((g)     ^ x7) * 4);
    float4 rb = *reinterpret_cast<const float4*>(tb + ((4 + g) ^ x7) * 4);
    float xs[8] = {ra.x, ra.y, ra.z, ra.w, rb.x, rb.y, rb.z, rb.w};
    bf16x8 ahi, alo;
    cvt8(xs, ahi, alo);
    // B frags: two float2 (k-groups 4g and 16+4g) per (ntile, part)
    const int U1 = c * 8 + g, U2 = U1 + 4;
    union BU { float2 f[2]; bf16x8 v; };
    BU b0h, b0l, b1h, b1l;
    {
      const int o1 = ce0 * 1024 + ((U1 ^ x7) << 2);
      const int o2 = ce0 * 1024 + ((U2 ^ x7) << 2);
      b0h.f[0] = *(const float2*)(Whi + o1); b0h.f[1] = *(const float2*)(Whi + o2);
      b0l.f[0] = *(const float2*)(Wlo + o1); b0l.f[1] = *(const float2*)(Wlo + o2);
    }
    {
      const int o1 = ce1 * 1024 + ((U1 ^ ce1_7) << 2);
      const int o2 = ce1 * 1024 + ((U2 ^ ce1_7) << 2);
      b1h.f[0] = *(const float2*)(Whi + o1); b1h.f[1] = *(const float2*)(Whi + o2);
      b1l.f[0] = *(const float2*)(Wlo + o1); b1l.f[1] = *(const float2*)(Wlo + o2);
    }
    acc0 = __builtin_amdgcn_mfma_f32_16x16x32_bf16(ahi, b0h.v, acc0, 0, 0, 0);
    acc0 = __builtin_amdgcn_mfma_f32_16x16x32_bf16(alo, b0h.v, acc0, 0, 0, 0);
    acc0 = __builtin_amdgcn_mfma_f32_16x16x32_bf16(ahi, b0l.v, acc0, 0, 0, 0);
    acc1 = __builtin_amdgcn_mfma_f32_16x16x32_bf16(ahi, b1h.v, acc1, 0, 0, 0);
    acc1 = __builtin_amdgcn_mfma_f32_16x16x32_bf16(alo, b1h.v, acc1, 0, 0, 0);
    acc1 = __builtin_amdgcn_mfma_f32_16x16x32_bf16(ahi, b1l.v, acc1, 0, 0, 0);
  };

  // ---- prologue: 3 chunks in flight (6 loads) ----
  stage(0); stage(1); stage(2);

  // ---- main loop: counted vmcnt, zero barriers ----
  for (int c = 0; c < 30; ++c) {
    asm volatile("s_waitcnt vmcnt(4)" ::: "memory");   // chunk c resident
    __builtin_amdgcn_sched_barrier(0);
    if (c < 29) stage(c + 3);
    compute(c);
  }
  asm volatile("s_waitcnt vmcnt(2)" ::: "memory");
  __builtin_amdgcn_sched_barrier(0);
  compute(30);
  asm volatile("s_waitcnt vmcnt(0)" ::: "memory");
  __builtin_amdgcn_sched_barrier(0);
  compute(31);

  // ---- epilogue: direct stores (D: col=l&15, row=4*(l>>4)+reg) ----
  const float bias0 = bias[ce0];
  const float bias1 = m5 ? bias[16 + (lane & 15)] : 0.f;
  const int rbase = row0 + 16 * w + 4 * (lane >> 4);
#pragma unroll
  for (int reg = 0; reg < 4; ++reg) {
    const int r = rbase + reg;
    out[(size_t)r * CC + ce0] = acc0[reg] + bias0;
    if (m5) out[(size_t)r * CC + 16 + (lane & 15)] = acc1[reg] + bias1;
  }
}

// ---------------------------------------------------------------------------
// Kernel 2: CRF NLL — unchanged (isolating the GEMM change).
// ---------------------------------------------------------------------------
__global__ __launch_bounds__(128) void crf_kernel(const float* __restrict__ em,
                                                  const float* __restrict__ trans,
                                                  const float* __restrict__ startT,
                                                  const float* __restrict__ endT,
                                                  const int* __restrict__ att,
                                                  const int* __restrict__ labels,
                                                  float* __restrict__ loss) {
  const int b    = blockIdx.x;
  const int tid  = threadIdx.x;
  const int wave = tid >> 6;
  const int lane = tid & 63;
  __shared__ float sh_num;
  __shared__ int   sh_len;

  const float L2E = 1.4426950408889634f;
  const float LN2 = 0.6931471805599453f;

  if (wave == 1) {
    int cnt = 0;
    for (int t = lane; t < TT; t += 64) {
      bool m = (t == 0) || ((att[b * TT + t] != 0) && (labels[b * TT + t] != -100));
      cnt += m ? 1 : 0;
    }
#pragma unroll
    for (int off = 32; off >= 1; off >>= 1) cnt += __shfl_down(cnt, off);
    cnt = __shfl(cnt, 0);

    float s = 0.f;
    for (int t = lane + 1; t < TT; t += 64) {
      bool m = (att[b * TT + t] != 0) && (labels[b * TT + t] != -100);
      if (m) {
        int tp = labels[b * TT + t - 1], tc = labels[b * TT + t];
        s += trans[tp * CC + tc] + em[((size_t)b * TT + t) * CC + tc];
      }
    }
#pragma unroll
    for (int off = 32; off >= 1; off >>= 1) s += __shfl_down(s, off);
    if (lane == 0) {
      int tag0 = labels[b * TT];
      int lastTag = labels[b * TT + cnt - 1];
      s += startT[tag0] + em[((size_t)b * TT) * CC + tag0] + endT[lastTag];
      sh_num = s;
      sh_len = cnt;
    }
  }

  const int j = lane < CC ? lane : CC - 1;
  float E[CC];
  float beta = 0.f, endE = 0.f;
  if (wave == 0) {
#pragma unroll
    for (int i = 0; i < CC; ++i)
      E[i] = __builtin_amdgcn_exp2f(trans[i * CC + j] * L2E);
    beta = __builtin_amdgcn_exp2f((startT[j] + em[((size_t)b * TT) * CC + j]) * L2E);
    endE = __builtin_amdgcn_exp2f(endT[j] * L2E);
  }
  __syncthreads();

  if (wave == 0) {
    const int len = sh_len;
    int ksum = 0;

    float sb[CC];
#pragma unroll
    for (int i = 0; i < CC; ++i)
      sb[i] = __int_as_float(__builtin_amdgcn_readlane(__float_as_int(beta), i));

    const float* emB = em + (size_t)b * TT * CC;

    auto step = [&](float em_v) {
      float pm = __builtin_amdgcn_exp2f(em_v * L2E);
      int ef = (__float_as_int(sb[0]) >> 23) & 255;
      ksum += ef - 127;
      float pms = pm * __int_as_float((254 - ef) << 23);
      float c0 = 0.f, c1 = 0.f, c2 = 0.f;
#pragma unroll
      for (int i = 0; i < CC; i += 3) c0 = fmaf(sb[i], E[i], c0);
#pragma unroll
      for (int i = 1; i < CC; i += 3) c1 = fmaf(sb[i], E[i], c1);
#pragma unroll
      for (int i = 2; i < CC; i += 3) c2 = fmaf(sb[i], E[i], c2);
      beta = ((c0 + c1) + c2) * pms;
#pragma unroll
      for (int i = 0; i < CC; ++i)
        sb[i] = __int_as_float(__builtin_amdgcn_readlane(__float_as_int(beta), i));
    };

    float r[8];
#pragma unroll
    for (int u = 0; u < 8; ++u) {
      int tt = 1 + u; if (tt > len - 1) tt = len - 1;
      r[u] = emB[(size_t)tt * CC + j];
    }

    int t = 1;
    for (; t + 8 <= len; t += 8) {
#pragma unroll
      for (int u = 0; u < 8; ++u) {
        int tp = t + u + 8; if (tp > len - 1) tp = len - 1;
        float rn = emB[(size_t)tp * CC + j];
        step(r[u]);
        r[u] = rn;
      }
    }
    for (; t < len; ++t) {
      step(r[0]);
#pragma unroll
      for (int u = 0; u < 7; ++u) r[u] = r[u + 1];
    }

    float v = (lane < CC) ? beta * endE : 0.f;
#pragma unroll
    for (int off = 32; off >= 1; off >>= 1) v += __shfl_xor(v, off);
    if (lane == 0) {
      float logZ = (float)ksum * LN2 + LN2 * __builtin_amdgcn_logf(v);
      atomicAdd(loss, -(sh_num - logZ) * (1.0f / 64.0f));
    }
  }
}

extern "C" void kernel_launch(void* const* d_in, const int* in_sizes, int n_in,
                              void* d_out, int out_size, void* d_ws, size_t ws_size,
                              hipStream_t stream) {
  const float* hs     = (const float*)d_in[0];
  const float* W      = (const float*)d_in[1];
  const float* bias   = (const float*)d_in[2];
  const float* trans  = (const float*)d_in[3];
  const float* startT = (const float*)d_in[4];
  const float* endT   = (const float*)d_in[5];
  const int*   att    = (const int*)d_in[6];
  const int*   labels = (const int*)d_in[7];
  float* out = (float*)d_out;

  emis_gemm<<<dim3(256), dim3(512), 0, stream>>>(hs, W, bias, out);
  crf_kernel<<<dim3(64), dim3(128), 0, stream>>>(out, trans, startT, endT, att,
                                                 labels, out + (size_t)NROWS * CC);
}